// Round 12
// baseline (503.682 us; speedup 1.0000x reference)
//
#include <hip/hip_runtime.h>

typedef unsigned short u16;
typedef short short8 __attribute__((ext_vector_type(8)));
typedef float f32x4 __attribute__((ext_vector_type(4)));
typedef unsigned short u16x4 __attribute__((ext_vector_type(4)));

__device__ __forceinline__ u16 f2bf(float f) {
  unsigned u = __builtin_bit_cast(unsigned, f);
  u += 0x7fffu + ((u >> 16) & 1u);
  return (u16)(u >> 16);
}
__device__ __forceinline__ float bf2f(u16 s) {
  unsigned u = ((unsigned)s) << 16;
  return __builtin_bit_cast(float, u);
}
// packed f32x2 -> bf16x2 (lo = a, hi = b), RNE — gfx950 has no builtin (T12)
__device__ __forceinline__ unsigned cvtpk_bf16(float a, float b) {
  unsigned r;
  asm("v_cvt_pk_bf16_f32 %0, %1, %2" : "=v"(r) : "v"(a), "v"(b));
  return r;
}

#if __has_builtin(__builtin_amdgcn_exp2f)
#define EXP2F(x) __builtin_amdgcn_exp2f(x)
#else
#define EXP2F(x) exp2f(x)
#endif

#define MFMA32(a, b, c) __builtin_amdgcn_mfma_f32_16x16x32_bf16(a, b, c, 0, 0, 0)

#define GLDS16(gp, lp)                                                         \
  __builtin_amdgcn_global_load_lds(                                            \
      (__attribute__((address_space(1))) void*)(gp),                           \
      (__attribute__((address_space(3))) void*)(lp), 16, 0, 0)

// ---------------- cast fp32 -> bf16 ----------------
__global__ __launch_bounds__(256) void cast_bf16_k(const float* __restrict__ in,
                                                   u16* __restrict__ out, int n4) {
  int i = blockIdx.x * 256 + threadIdx.x;
  if (i >= n4) return;
  float4 v = ((const float4*)in)[i];
  u16x4 o = { f2bf(v.x), f2bf(v.y), f2bf(v.z), f2bf(v.w) };
  ((u16x4*)out)[i] = o;
}

// ---------------- weight transpose+cast: Wt[n][k] = W[k][n] ----------------
__global__ __launch_bounds__(256) void transw_k(const float* W0, const float* W1,
                                                const float* W2, const float* W3,
                                                const float* W4, const float* W5,
                                                u16* __restrict__ Wt) {
  int z = blockIdx.z;
  const float* W = z == 0 ? W0 : z == 1 ? W1 : z == 2 ? W2 : z == 3 ? W3 : z == 4 ? W4 : W5;
  u16* T = Wt + (size_t)z * 2048 * 2048;
  __shared__ float tile[64][65];
  int k0 = blockIdx.x * 64, n0 = blockIdx.y * 64;
  int c4 = (threadIdx.x & 15) * 4;
  int r = threadIdx.x >> 4;  // 0..15
#pragma unroll
  for (int i = 0; i < 4; ++i) {
    int row = r + i * 16;
    float4 v = *(const float4*)(W + (size_t)(k0 + row) * 2048 + n0 + c4);
    tile[row][c4 + 0] = v.x; tile[row][c4 + 1] = v.y;
    tile[row][c4 + 2] = v.z; tile[row][c4 + 3] = v.w;
  }
  __syncthreads();
#pragma unroll
  for (int i = 0; i < 4; ++i) {
    int nrow = r + i * 16;
    u16x4 o = { f2bf(tile[c4 + 0][nrow]), f2bf(tile[c4 + 1][nrow]),
                f2bf(tile[c4 + 2][nrow]), f2bf(tile[c4 + 3][nrow]) };
    *(u16x4*)(T + (size_t)(n0 + nrow) * 2048 + k0 + c4) = o;
  }
}

// ---------------- small-M GEMM (K/V projections): out = A * Wt^T + bias ----------------
struct GemmJob {
  const u16* A; const u16* Bt; const float* bias; void* out;
  int M; int mode; int ldo;
};
struct GemmJobs { GemmJob j[8]; };

__global__ __launch_bounds__(256) void gemm_k(GemmJobs jobs) {
  GemmJob J = jobs.j[blockIdx.z];
  const int m0 = blockIdx.x * 128;
  if (m0 >= J.M) return;
  const int n0 = blockIdx.y * 128;
  __shared__ u16 Asm[2][128 * 32];
  __shared__ u16 Bsm[2][128 * 32];
  const int tid = threadIdx.x;
  const int lane = tid & 63;
  const int l15 = lane & 15, quad = lane >> 4;
  const int wave = tid >> 6;
  const int wr = (wave >> 1) * 64, wc = (wave & 1) * 64;
  f32x4 acc[4][4] = {};
  const int g0 = tid, g1 = tid + 256;
  const u16* ag0 = J.A + (size_t)(m0 + (g0 >> 2)) * 2048 + (g0 & 3) * 8;
  const u16* ag1 = J.A + (size_t)(m0 + (g1 >> 2)) * 2048 + (g1 & 3) * 8;
  const u16* bg0 = J.Bt + (size_t)(n0 + (g0 >> 2)) * 2048 + (g0 & 3) * 8;
  const u16* bg1 = J.Bt + (size_t)(n0 + (g1 >> 2)) * 2048 + (g1 & 3) * 8;

  auto stage = [&](int buf, int k0) {
    GLDS16(ag0 + k0, &Asm[buf][g0 * 8]);
    GLDS16(ag1 + k0, &Asm[buf][g1 * 8]);
    GLDS16(bg0 + k0, &Bsm[buf][g0 * 8]);
    GLDS16(bg1 + k0, &Bsm[buf][g1 * 8]);
  };
  stage(0, 0);
  for (int k0 = 0; k0 < 2048; k0 += 32) {
    const int cb = (k0 >> 5) & 1;
    __syncthreads();  // drains tile's loads, issued a full K-step ago
    if (k0 + 32 < 2048) stage(cb ^ 1, k0 + 32);
    short8 af[4], bf[4];
#pragma unroll
    for (int mi = 0; mi < 4; ++mi)
      af[mi] = *(const short8*)(&Asm[cb][(wr + mi * 16 + l15) * 32 + quad * 8]);
#pragma unroll
    for (int ni = 0; ni < 4; ++ni)
      bf[ni] = *(const short8*)(&Bsm[cb][(wc + ni * 16 + l15) * 32 + quad * 8]);
    __builtin_amdgcn_s_setprio(1);
#pragma unroll
    for (int mi = 0; mi < 4; ++mi)
#pragma unroll
      for (int ni = 0; ni < 4; ++ni)
        acc[mi][ni] = __builtin_amdgcn_mfma_f32_16x16x32_bf16(af[mi], bf[ni], acc[mi][ni], 0, 0, 0);
    __builtin_amdgcn_s_setprio(0);
  }
#pragma unroll
  for (int mi = 0; mi < 4; ++mi) {
#pragma unroll
    for (int ni = 0; ni < 4; ++ni) {
      int nn = n0 + wc + ni * 16 + l15;
      float bv = J.bias[nn];
#pragma unroll
      for (int r = 0; r < 4; ++r) {
        int mm = m0 + wr + mi * 16 + quad * 4 + r;
        if (mm >= J.M) continue;
        float v = acc[mi][ni][r] + bv;
        if (J.mode == 0) {
          ((u16*)J.out)[(size_t)mm * J.ldo + nn] = f2bf(v);
        } else if (J.mode == 1) {
          int ml = mm & 31;
          int mp = (mm & ~31) | (((ml >> 2) & 3) * 8 + (ml >> 4) * 4 + (ml & 3));
          ((u16*)J.out)[(size_t)nn * J.ldo + mp] = f2bf(v);
        } else {
          ((float*)J.out)[(size_t)mm * J.ldo + nn] = v;
        }
      }
    }
  }
}

// ---------------- big GEMM: 256x256, BK=64, m201-style 8-phase schedule ----------------
// R8 (T3+T4, regime-correct): 2 K-tile LDS buffers (buf = kt&1, 128 KiB — R6/R7
// already ran 128 KiB static successfully). 8 phases per iter, 2 K-tiles/iter.
// Phase p (0-based): {ds-read quadrant frags [+ all B frags at p%4==0] ;
// stage ONE half-tile ; [vmcnt gate at p3/p7] ; s_barrier ; lgkmcnt(0) ;
// sched_barrier ; 16 MFMA ; s_barrier}. Region-safety (stage only after the
// region's last read completed, proven via the barrier+lgkm protocol):
//   p0/p1: A-top/bot(2i+1)->buf1  (buf1-A last read p7 of iter i-1)
//   p2/p3: B-top/bot(2i+2)->buf0  (buf0-B read only at p0)
//   p4/p5: A-top/bot(2i+2)->buf0  (buf0-A last read p3)
//   p6/p7: B-top/bot(2i+3)->buf1  (buf1-B read only at p4)
// vmcnt(4) at p3 guarantees p0/p1 (A for the p4..p7 tile) landed while p2/p3
// stay in flight; vmcnt(4) at p7 guarantees p4/p5 landed for next iter's p0.
// Queue never drains in the main loop (T4). Last iter: skip kt>=32 stages,
// gates become vmcnt(0). Iter 0: p0/p1 skipped (tile 1 staged in prologue).
__global__ __launch_bounds__(512, 2) void gemm256_k(const u16* __restrict__ A,
                                                    const u16* __restrict__ Bt,
                                                    const float* __restrict__ bias,
                                                    void* __restrict__ out,
                                                    int mode) {
  const int m0 = blockIdx.x * 256, n0 = blockIdx.y * 256;
  __shared__ u16 lds[2][2][2][128 * 64];  // [buf][op A/B][half][row*64+col], 128 KiB
  const int tid = threadIdx.x, lane = tid & 63;
  const int l15 = lane & 15, quad = lane >> 4;
  const int wave = tid >> 6;
  const int wr = wave >> 2;   // 0..1 : A half (128 rows)
  const int wc = wave & 3;    // 0..3 : B quarter (64 cols); B half = wc>>1
  f32x4 acc[8][4] = {};

  // stage one half-tile (128 rows x 64 cols of one operand): 2 loads/thread.
  // LDS linear; source chunk pre-swizzled (c&7)^(row&7) (rule 21).
  auto stageH = [&](int op, int half, int kt) {
    const int buf = kt & 1;
    const u16* base = (op == 0 ? A + (size_t)(m0 + half * 128) * 2048
                               : Bt + (size_t)(n0 + half * 128) * 2048) + kt * 64;
#pragma unroll
    for (int jj = 0; jj < 2; ++jj) {
      const int c = tid + 512 * jj;
      const int row = c >> 3;
      const int scc = ((c & 7) ^ (row & 7)) * 8;
      GLDS16(base + (size_t)row * 2048 + scc, &lds[buf][op][half][(size_t)c * 8]);
    }
  };

  // prologue: tiles 0 and 1 in full (16 loads/thread)
  stageH(0, 0, 0); stageH(0, 1, 0); stageH(1, 0, 0); stageH(1, 1, 0);
  stageH(0, 0, 1); stageH(0, 1, 1); stageH(1, 0, 1); stageH(1, 1, 1);
  asm volatile("s_waitcnt vmcnt(8)" ::: "memory");  // tile 0 landed; tile 1 in flight
  __builtin_amdgcn_s_barrier();

  for (int i = 0; i < 16; ++i) {
#pragma unroll
    for (int hi = 0; hi < 2; ++hi) {  // K-tile T = 2i+hi from buf hi
      const int buf = hi;
      short8 bfr[2][4], af[2][2];
#pragma unroll
      for (int q = 0; q < 4; ++q) {
        if (q == 0) {  // all B frags for this tile (8 ds_read_b128)
#pragma unroll
          for (int kc = 0; kc < 2; ++kc)
#pragma unroll
            for (int ni = 0; ni < 4; ++ni) {
              const int r = (wc * 64 + ni * 16 + l15) & 127;
              bfr[kc][ni] = *(const short8*)(
                  &lds[buf][1][wc >> 1][r * 64 + (((kc * 4 + quad) ^ (r & 7)) * 8)]);
            }
        }
        // A frags for this quadrant (4 ds_read_b128)
#pragma unroll
        for (int kc = 0; kc < 2; ++kc)
#pragma unroll
          for (int m2 = 0; m2 < 2; ++m2) {
            const int r = (q * 2 + m2) * 16 + l15;  // 0..127 within half wr
            af[kc][m2] = *(const short8*)(
                &lds[buf][0][wr][r * 64 + (((kc * 4 + quad) ^ (r & 7)) * 8)]);
          }
        // stage one half-tile per phase (mapping in header comment)
        {
          const int p = hi * 4 + q;
          const int op = (p == 2 || p == 3 || p == 6 || p == 7) ? 1 : 0;
          const int hf = p & 1;
          const int kt = (p < 2) ? (2 * i + 1) : ((p < 6) ? (2 * i + 2) : (2 * i + 3));
          if (kt < 32 && !(i == 0 && p < 2)) stageH(op, hf, kt);
        }
        if (q == 3) {  // phases 4 and 8 (1-based): counted gate, never 0 mid-loop
          if (i < 15) asm volatile("s_waitcnt vmcnt(4)" ::: "memory");
          else        asm volatile("s_waitcnt vmcnt(0)" ::: "memory");
        }
        __builtin_amdgcn_s_barrier();
        asm volatile("s_waitcnt lgkmcnt(0)" ::: "memory");
        __builtin_amdgcn_sched_barrier(0);  // rule 18: pin MFMA below the wait
        __builtin_amdgcn_s_setprio(1);
#pragma unroll
        for (int m2 = 0; m2 < 2; ++m2)
#pragma unroll
          for (int ni = 0; ni < 4; ++ni) {
            acc[q * 2 + m2][ni] = MFMA32(af[0][m2], bfr[0][ni], acc[q * 2 + m2][ni]);
            acc[q * 2 + m2][ni] = MFMA32(af[1][m2], bfr[1][ni], acc[q * 2 + m2][ni]);
          }
        __builtin_amdgcn_s_setprio(0);
        __builtin_amdgcn_s_barrier();
      }
    }
  }
#pragma unroll
  for (int mi = 0; mi < 8; ++mi) {
#pragma unroll
    for (int ni = 0; ni < 4; ++ni) {
      const int nn = n0 + wc * 64 + ni * 16 + l15;
      const float bv = bias[nn];
      const int mm = m0 + wr * 128 + mi * 16 + quad * 4;
      if (mode == 0) {
        u16* op = (u16*)out + (size_t)mm * 2048 + nn;
#pragma unroll
        for (int r = 0; r < 4; ++r) op[(size_t)r * 2048] = f2bf(acc[mi][ni][r] + bv);
      } else {
        float* op = (float*)out + (size_t)mm * 2048 + nn;
#pragma unroll
        for (int r = 0; r < 4; ++r) op[(size_t)r * 2048] = acc[mi][ni][r] + bv;
      }
    }
  }
}

// ---------------- RMSNorm in place (rows of 2048 bf16) ----------------
__global__ __launch_bounds__(256) void rmsnorm_k(u16* __restrict__ buf,
                                                 const float* __restrict__ g) {
  const int row = blockIdx.x, tid = threadIdx.x;
  u16* p = buf + (size_t)row * 2048 + tid * 8;
  short8 v = *(short8*)p;
  float x[8]; float s = 0.f;
#pragma unroll
  for (int i = 0; i < 8; ++i) { x[i] = bf2f((u16)v[i]); s += x[i] * x[i]; }
#pragma unroll
  for (int o = 1; o < 64; o <<= 1) s += __shfl_xor(s, o, 64);
  __shared__ float ws4[4];
  if ((tid & 63) == 0) ws4[tid >> 6] = s;
  __syncthreads();
  float tot = ws4[0] + ws4[1] + ws4[2] + ws4[3];
  float scale = rsqrtf(tot * (1.0f / 2048.0f) + 1e-6f);
  const float* gp = g + tid * 8;
  short8 o8;
#pragma unroll
  for (int i = 0; i < 8; ++i) o8[i] = (short)f2bf(x[i] * scale * gp[i]);
  *(short8*)p = o8;
}

// ---------------- flash attention ----------------
// R8: uniform work per block — each block handles its (h,qx) for BOTH
// batches serially (img0+txt0 then img1+txt1). Every block now does
// 10 + ceil(l0/64) + ceil(l1/64) tiles — identical chip-wide, so the
// finish-time tail that capped occupancy at 19% (txt tiles vary 1..8 per
// batch) is gone. Grid 256 = 1 block/CU. KVBLK=64, defer-max, swizzles
// unchanged from R4/R5.
__global__ __launch_bounds__(512) void attn_k(const u16* __restrict__ Q,
                                              const u16* __restrict__ Kt,
                                              const u16* __restrict__ Vt,
                                              const u16* __restrict__ Ki,
                                              const u16* __restrict__ Vi,
                                              const int* __restrict__ lens,
                                              u16* __restrict__ out) {
  const int lid = blockIdx.x + 16 * blockIdx.y;  // [0,256)
  const int xcd = lid & 7, j = lid >> 3;         // j in [0,32)
  const int h = xcd * 2 + (j & 1);               // 2 heads per XCD
  const int qx = j >> 1;                         // [0,16)

  const int tid = threadIdx.x, lane = tid & 63, wave = tid >> 6;
  const int l15 = lane & 15, quad = lane >> 4;
  const int qbase = qx * 256 + wave * 32;
  const float scale2 = 0.12752358514837517f;  // (1/sqrt(128)) * log2(e)
  const float NEGINF = -__builtin_inff();
  __shared__ u16 Ksm[2][2][32 * 128];  // [buf][sub][row*128+c], cc' = cc ^ (row&7)
  __shared__ u16 Vsm[2][2][128 * 32];  // [buf][sub][d*32+c], chunk' = chunk ^ ((d>>1)&3)

  const int krow = tid >> 4;                           // 0..31
  const int kcc = ((tid & 15) ^ (krow & 7)) * 8;       // swizzled K source col
  const int vd = tid >> 2;                             // 0..127
  const int vcs = ((tid & 3) ^ ((vd >> 1) & 3)) * 8;   // swizzled V source chunk
  const int kxor = l15 & 7;
  const int vxor = (l15 >> 1) & 3;

  short8 qf[2][4];
  f32x4 accv[2][8];
  u16x4 oimg[2][8];
  float run_m[2], run_l[2];

  auto phase = [&](const u16* Kb, const u16* Vb, int Lv, int LK) {
    run_m[0] = run_m[1] = NEGINF;
    run_l[0] = run_l[1] = 0.f;
#pragma unroll
    for (int h2 = 0; h2 < 2; ++h2)
#pragma unroll
      for (int dt = 0; dt < 8; ++dt)
#pragma unroll
        for (int r = 0; r < 4; ++r) accv[h2][dt][r] = 0.f;
    const u16* kg = Kb + (size_t)krow * 2048 + kcc;
    const u16* vg = Vb + (size_t)vd * LK + vcs;
    const int ntiles = (Lv + 63) >> 6;
    auto stage = [&](int buf, int t) {
      const int kvA = t * 64;
      const int sA = (kvA < LK - 32) ? kvA : (LK - 32);
      const int sB = (kvA + 32 < LK - 32) ? (kvA + 32) : (LK - 32);
      GLDS16(kg + (size_t)sA * 2048, &Ksm[buf][0][tid * 8]);
      GLDS16(kg + (size_t)sB * 2048, &Ksm[buf][1][tid * 8]);
      GLDS16(vg + sA, &Vsm[buf][0][tid * 8]);
      GLDS16(vg + sB, &Vsm[buf][1][tid * 8]);
    };
    stage(0, 0);
    __syncthreads();
    for (int t = 0; t < ntiles; ++t) {
      const int cb = t & 1;
      if (t + 1 < ntiles) stage(cb ^ 1, t + 1);

      // ---- QK^T: 4 key-16-blocks ----
      f32x4 s[2][4];
#pragma unroll
      for (int h2 = 0; h2 < 2; ++h2)
#pragma unroll
        for (int kb = 0; kb < 4; ++kb)
#pragma unroll
          for (int r = 0; r < 4; ++r) s[h2][kb][r] = 0.f;
      {
        short8 kA[2][4];
#pragma unroll
        for (int kc = 0; kc < 4; ++kc) {
          const int c0 = ((kc * 4 + quad) ^ kxor) * 8;
          kA[0][kc] = *(const short8*)(&Ksm[cb][0][l15 * 128 + c0]);
          kA[1][kc] = *(const short8*)(&Ksm[cb][0][(16 + l15) * 128 + c0]);
        }
        __builtin_amdgcn_s_setprio(1);
#pragma unroll
        for (int h2 = 0; h2 < 2; ++h2)
#pragma unroll
          for (int kc = 0; kc < 4; ++kc) {
            s[h2][0] = MFMA32(kA[0][kc], qf[h2][kc], s[h2][0]);
            s[h2][1] = MFMA32(kA[1][kc], qf[h2][kc], s[h2][1]);
          }
        __builtin_amdgcn_s_setprio(0);
      }
      {
        short8 kB[2][4];
#pragma unroll
        for (int kc = 0; kc < 4; ++kc) {
          const int c0 = ((kc * 4 + quad) ^ kxor) * 8;
          kB[0][kc] = *(const short8*)(&Ksm[cb][1][l15 * 128 + c0]);
          kB[1][kc] = *(const short8*)(&Ksm[cb][1][(16 + l15) * 128 + c0]);
        }
        __builtin_amdgcn_s_setprio(1);
#pragma unroll
        for (int h2 = 0; h2 < 2; ++h2)
#pragma unroll
          for (int kc = 0; kc < 4; ++kc) {
            s[h2][2] = MFMA32(kB[0][kc], qf[h2][kc], s[h2][2]);
            s[h2][3] = MFMA32(kB[1][kc], qf[h2][kc], s[h2][3]);
          }
        __builtin_amdgcn_s_setprio(0);
      }

      // ---- tail mask in RAW score units ----
      const int kvA = t * 64;
      if (kvA + 64 > Lv) {
#pragma unroll
        for (int h2 = 0; h2 < 2; ++h2)
#pragma unroll
          for (int kb = 0; kb < 4; ++kb)
#pragma unroll
            for (int r = 0; r < 4; ++r) {
              const int ki = kvA + kb * 16 + quad * 4 + r;
              if (ki >= Lv) s[h2][kb][r] = NEGINF;
            }
      }

      // ---- one softmax pass over 64 keys (defer-max, THR = 62 raw = 2^8) ----
      float al[2];
      short8 pfA[2], pfB[2];
#pragma unroll
      for (int h2 = 0; h2 < 2; ++h2) {
        float m0 = fmaxf(fmaxf(s[h2][0][0], s[h2][0][1]), fmaxf(s[h2][0][2], s[h2][0][3]));
        float m1 = fmaxf(fmaxf(s[h2][1][0], s[h2][1][1]), fmaxf(s[h2][1][2], s[h2][1][3]));
        float m2 = fmaxf(fmaxf(s[h2][2][0], s[h2][2][1]), fmaxf(s[h2][2][2], s[h2][2][3]));
        float m3 = fmaxf(fmaxf(s[h2][3][0], s[h2][3][1]), fmaxf(s[h2][3][2], s[h2][3][3]));
        float mx = fmaxf(fmaxf(m0, m1), fmaxf(m2, m3));
        mx = fmaxf(mx, __shfl_xor(mx, 16, 64));
        mx = fmaxf(mx, __shfl_xor(mx, 32, 64));
        const float nm = (mx - run_m[h2] > 62.0f) ? mx : run_m[h2];
        al[h2] = EXP2F((run_m[h2] - nm) * scale2);
        run_m[h2] = nm;
        const float nmc = -nm * scale2;
        float p[4][4], psum = 0.f;
#pragma unroll
        for (int kb = 0; kb < 4; ++kb)
#pragma unroll
          for (int r = 0; r < 4; ++r) {
            p[kb][r] = EXP2F(__builtin_fmaf(s[h2][kb][r], scale2, nmc));
            psum += p[kb][r];
          }
        run_l[h2] = __builtin_fmaf(run_l[h2], al[h2], psum);
        union { short8 s8; unsigned u[4]; } pa, pb;
        pa.u[0] = cvtpk_bf16(p[0][0], p[0][1]);
        pa.u[1] = cvtpk_bf16(p[0][2], p[0][3]);
        pa.u[2] = cvtpk_bf16(p[1][0], p[1][1]);
        pa.u[3] = cvtpk_bf16(p[1][2], p[1][3]);
        pb.u[0] = cvtpk_bf16(p[2][0], p[2][1]);
        pb.u[1] = cvtpk_bf16(p[2][2], p[2][3]);
        pb.u[2] = cvtpk_bf16(p[3][0], p[3][1]);
        pb.u[3] = cvtpk_bf16(p[3][2], p[3][3]);
        pfA[h2] = pa.s8;
        pfB[h2] = pb.s8;
      }
      if (t != 0 && __ballot((al[0] < 1.0f) || (al[1] < 1.0f))) {
#pragma unroll
        for (int h2 = 0; h2 < 2; ++h2)
#pragma unroll
          for (int dt = 0; dt < 8; ++dt)
#pragma unroll
            for (int r = 0; r < 4; ++r) accv[h2][dt][r] *= al[h2];
      }

      // ---- PV: both 32-key halves ----
      __builtin_amdgcn_s_setprio(1);
#pragma unroll
      for (int dt = 0; dt < 8; ++dt) {
        const int vo = (dt * 16 + l15) * 32 + ((quad ^ vxor) * 8);
        short8 vfA = *(const short8*)(&Vsm[cb][0][vo]);
        short8 vfB = *(const short8*)(&Vsm[cb][1][vo]);
        accv[0][dt] = MFMA32(vfA, pfA[0], accv[0][dt]);
        accv[1][dt] = MFMA32(vfA, pfA[1], accv[1][dt]);
        accv[0][dt] = MFMA32(vfB, pfB[0], accv[0][dt]);
        accv[1][dt] = MFMA32(vfB, pfB[1], accv[1][dt]);
      }
      __builtin_amdgcn_s_setprio(0);
      __syncthreads();
    }
  };

  for (int b = 0; b < 2; ++b) {
    // Q fragments for this batch
#pragma unroll
    for (int h2 = 0; h2 < 2; ++h2) {
      const u16* qb = Q + ((size_t)(b * 4096 + qbase + h2 * 16 + l15)) * 2048 + h * 128 + quad * 8;
#pragma unroll
      for (int kc = 0; kc < 4; ++kc) qf[h2][kc] = *(const short8*)(qb + kc * 32);
    }
    // ---- img phase ----
    const u16* Kb_i = Ki + (size_t)(b * 288) * 2048 + h * 128;
    const u16* Vb_i = Vi + ((size_t)(b * 16 + h) * 128) * 288;
    phase(Kb_i, Vb_i, 257, 288);
#pragma unroll
    for (int h2 = 0; h2 < 2; ++h2) {
      float a = run_l[h2] + __shfl_xor(run_l[h2], 16, 64);
      float lt = a + __shfl_xor(a, 32, 64);
      float inv = 1.0f / lt;
#pragma unroll
      for (int dt = 0; dt < 8; ++dt) {
        u16x4 w2 = { f2bf(accv[h2][dt][0] * inv), f2bf(accv[h2][dt][1] * inv),
                     f2bf(accv[h2][dt][2] * inv), f2bf(accv[h2][dt][3] * inv) };
        oimg[h2][dt] = w2;
      }
    }
    // ---- txt phase ----
    const u16* Kb_t = Kt + (size_t)(b * 512) * 2048 + h * 128;
    const u16* Vb_t = Vt + ((size_t)(b * 16 + h) * 128) * 512;
    phase(Kb_t, Vb_t, lens[b], 512);
#pragma unroll
    for (int h2 = 0; h2 < 2; ++h2) {
      float a = run_l[h2] + __shfl_xor(run_l[h2], 16, 64);
      float lt = a + __shfl_xor(a, 32, 64);
      float inv = 1.0f / lt;
      u16* ob = out + ((size_t)(b * 4096 + qbase + h2 * 16 + l15)) * 2048 + h * 128 + quad * 4;
#pragma unroll
      for (int dt = 0; dt < 8; ++dt) {
        u16x4 w2 = { f2bf(bf2f(oimg[h2][dt][0]) + accv[h2][dt][0] * inv),
                     f2bf(bf2f(oimg[h2][dt][1]) + accv[h2][dt][1] * inv),
                     f2bf(bf2f(oimg[h2][dt][2]) + accv[h2][dt][2] * inv),
                     f2bf(bf2f(oimg[h2][dt][3]) + accv[h2][dt][3] * inv) };
        *(u16x4*)(ob + dt * 16) = w2;
      }
    }
  }
}

extern "C" void kernel_launch(void* const* d_in, const int* in_sizes, int n_in,
                              void* d_out, int out_size, void* d_ws, size_t ws_size,
                              hipStream_t stream) {
  const float* x   = (const float*)d_in[0];
  const float* ctx = (const float*)d_in[1];
  const int* lens  = (const int*)d_in[2];
  const float* Wq  = (const float*)d_in[3];
  const float* bq  = (const float*)d_in[4];
  const float* gq  = (const float*)d_in[5];
  const float* Wk  = (const float*)d_in[6];
  const float* bk  = (const float*)d_in[7];
  const float* gk  = (const float*)d_in[8];
  const float* Wv  = (const float*)d_in[9];
  const float* bv  = (const float*)d_in[10];
  const float* Wki = (const float*)d_in[11];
  const float* bki = (const float*)d_in[12];
  const float* gki = (const float*)d_in[13];
  const float* Wvi = (const float*)d_in[14];
  const float* bvi = (const float*)d_in[15];
  const float* Wo  = (const float*)d_in[16];
  const float* bo  = (const float*)d_in[17];
  float* out = (float*)d_out;

  char* p = (char*)d_ws;
  u16* x_bf   = (u16*)p; p += (size_t)8192 * 2048 * 2;     // reused as attn_out
  u16* ctx_bf = (u16*)p; p += (size_t)2 * 769 * 2048 * 2;
  u16* Wt     = (u16*)p; p += (size_t)6 * 2048 * 2048 * 2;
  u16* Qb     = (u16*)p; p += (size_t)8192 * 2048 * 2;
  u16* Ktxt   = (u16*)p; p += (size_t)2 * 512 * 2048 * 2;
  u16* Vtt    = (u16*)p; p += (size_t)2 * 16 * 128 * 512 * 2;
  u16* Kimg   = (u16*)p; p += (size_t)2 * 288 * 2048 * 2;
  u16* Vti    = (u16*)p; p += (size_t)2 * 16 * 128 * 288 * 2;
  u16* attn_o = x_bf;

  cast_bf16_k<<<16384, 256, 0, stream>>>(x, x_bf, 8192 * 2048 / 4);
  cast_bf16_k<<<3076, 256, 0, stream>>>(ctx, ctx_bf, 2 * 769 * 2048 / 4);
  transw_k<<<dim3(32, 32, 6), 256, 0, stream>>>(Wq, Wk, Wv, Wki, Wvi, Wo, Wt);

  // Q projection: 8192x2048x2048 -> bf16
  gemm256_k<<<dim3(32, 8), 512, 0, stream>>>(x_bf, Wt + 0ull * 4194304, bq, Qb, 0);

  GemmJobs jc = {};
  for (int b = 0; b < 2; ++b) {
    const u16* txtA = ctx_bf + (size_t)(b * 769 + 257) * 2048;
    const u16* imgA = ctx_bf + (size_t)(b * 769) * 2048;
    jc.j[0 + b] = { txtA, Wt + 1ull * 4194304, bk,  Ktxt + (size_t)b * 512 * 2048, 512, 0, 2048 };
    jc.j[2 + b] = { txtA, Wt + 2ull * 4194304, bv,  Vtt  + (size_t)b * 2048 * 512, 512, 1, 512 };
    jc.j[4 + b] = { imgA, Wt + 3ull * 4194304, bki, Kimg + (size_t)b * 288 * 2048, 257, 0, 2048 };
    jc.j[6 + b] = { imgA, Wt + 4ull * 4194304, bvi, Vti  + (size_t)b * 2048 * 288, 257, 1, 288 };
  }
  gemm_k<<<dim3(4, 16, 8), 256, 0, stream>>>(jc);

  rmsnorm_k<<<8192, 256, 0, stream>>>(Qb, gq);
  rmsnorm_k<<<1024, 256, 0, stream>>>(Ktxt, gk);
  rmsnorm_k<<<576, 256, 0, stream>>>(Kimg, gki);

  attn_k<<<dim3(16, 16, 1), 512, 0, stream>>>(Qb, Ktxt, Vtt, Kimg, Vti, lens, attn_o);

  // output projection: 8192x2048x2048 -> fp32
  gemm256_k<<<dim3(32, 8), 512, 0, stream>>>(attn_o, Wt + 5ull * 4194304, bo, out, 1);
}